// Round 12
// baseline (967.378 us; speedup 1.0000x reference)
//
#include <hip/hip_runtime.h>
#include <hip/hip_bf16.h>
#include <math.h>

#define V 32000
#define D 256
#define L 4
#define E 4
#define S 4096
#define K_GATE 2201   // int(4096 * sigmoid(0.15)) = int(2201.31)
#define NCH 64        // stats chunks
#define SCHUNK 64     // tokens per stats chunk
#define CTS 136       // head C-tile LDS row stride (shorts); 272B=17*16 -> rows 16B-aligned

// Numerics rule (prior-session bisect): the expert GEMM must stay fp32-exact.
// fp32 VALU with k-ascending FMA chains is the proven-safe class. B stays bf16
// BITS in LDS (packed pairs), expanded to fp32 exactly at read (u<<16) -> every
// FMA sees identical fp32 operands in identical k=0..255 ascending order.
//   acc(s,f) = fma(x[s,k]*keep, W[e,f,k], acc) for k = 0..255 ascending
//   xo(s,f)  = sum over e ascending, skip excl: fin += (acc_e + bias_e)
//
// Occupancy rule (R3): k_moe keeps 256 thr x 512 blocks (2 blocks/CU, 2 w/SIMD).
// LDS-byte rule (R9/R10 measured): ~0.7 us end-to-end per B per k-pair cut;
// (M_t,N_t)=(4,2) is the byte-optimal shape at 256 threads -> lever exhausted.
// This round (T14): issue tile t+1 global loads to REGS before computing tile t,
// write LDS after the post-compute barrier. Same barrier count, same values,
// same order -> bit-identical; hides L2 latency under the FMA loop.

typedef __hip_bfloat16 bf16;
typedef __attribute__((ext_vector_type(8))) short bf16x8;
typedef __attribute__((ext_vector_type(4))) float f32x4;

__device__ __forceinline__ float loadf(const void* p, size_t i, int bf) {
    if (bf) return __bfloat162float(((const bf16*)p)[i]);
    return ((const float*)p)[i];
}
__device__ __forceinline__ float us2f(unsigned short u) {   // bf16 bits -> fp32 (exact)
    return __uint_as_float((unsigned)u << 16);
}

// async global->LDS, 16B per lane; LDS dest = wave-uniform base + lane*16
#define GLDS16(g, l)                                                            \
    __builtin_amdgcn_global_load_lds(                                           \
        (const __attribute__((address_space(1))) unsigned int*)(g),             \
        (__attribute__((address_space(3))) unsigned int*)(l), 16, 0, 0)

// Stage a 128x32 bf16 tile (8 KB) with XOR chunk swizzle (exonerated: bit-identical
// outputs). frag ds_read_b128 lands ~2-way conflict (free).
__device__ __forceinline__ void stage_tile(const bf16* __restrict__ src, int rowStride,
                                           short* lds, int t, int k0) {
    int w = t >> 6, l = t & 63;
    #pragma unroll
    for (int i = 0; i < 2; i++) {
        int chunk = (w * 2 + i) * 64 + l;
        int row = chunk >> 2;
        int c8 = (chunk & 3) ^ ((row >> 1) & 3);
        const bf16* g = src + (size_t)row * rowStride + k0 + c8 * 8;
        GLDS16(g, (char*)lds + (size_t)(w * 2 + i) * 1024);
    }
}

__device__ __forceinline__ bf16x8 frag_ld(const short* lds, int row, int quad) {
    return *(const bf16x8*)&lds[row * 32 + ((quad ^ ((row >> 1) & 3)) << 3)];
}

// ---------------- runtime dtype detection (bf16 vs fp32 inputs) ----------------
__global__ void k_detect(const void* __restrict__ emb, int* __restrict__ flag) {
    const unsigned short* h = (const unsigned short*)emb;
    int cnt = 0;
    for (int i = 0; i < 128; i += 2) {
        int e = (h[i] >> 7) & 0xFF;
        if (e >= 100 && e <= 130) cnt++;
    }
    *flag = (cnt >= 32) ? 1 : 0;
}

// ---------------- head weight -> bf16 (fp32-input fallback only) ----------------
__global__ void k_wcast(const void* __restrict__ W, const int* __restrict__ bfp,
                        bf16* __restrict__ Wb) {
    if (*bfp) return;   // bf16 inputs: head reads W directly
    size_t idx = ((size_t)blockIdx.x * 256 + threadIdx.x) * 4;
    float4 v = *(const float4*)((const float*)W + idx);
    Wb[idx + 0] = __float2bfloat16(v.x);
    Wb[idx + 1] = __float2bfloat16(v.y);
    Wb[idx + 2] = __float2bfloat16(v.z);
    Wb[idx + 3] = __float2bfloat16(v.w);
}

// ---------------- embedding gather ----------------
__global__ void k_embed(const int* __restrict__ tok, const void* __restrict__ emb,
                        const int* __restrict__ bfp, float* __restrict__ x) {
    int s = blockIdx.x, d = threadIdx.x;
    int bf = *bfp;
    int t = tok[s];
    x[s * D + d] = loadf(emb, (size_t)t * D + d, bf);
}

// ---------------- AstroNorm stats, phase 1: coalesced partial sums ----------------
__global__ void k_stats_part(const float* __restrict__ x, float* __restrict__ psum,
                             float* __restrict__ psq) {
    int b = blockIdx.x;        // NCH blocks
    int t = threadIdx.x;       // 256 = one feature per thread
    float s = 0.f, q = 0.f;
    int s0 = b * SCHUNK;
    #pragma unroll 4
    for (int i = 0; i < SCHUNK; i++) {
        float v = x[(size_t)(s0 + i) * D + t];
        s += v; q += v * v;
    }
    psum[b * D + t] = s;
    psq[b * D + t] = q;
}

// ------- AstroNorm finalize (per-block, redundant; bit-identical serial order) ---
// ------- + apply + context-gate score (wave per token) ---------------------------
__global__ void k_norm_score(float* __restrict__ x, const float* __restrict__ psum,
                             const float* __restrict__ psq,
                             const void* __restrict__ buffers, const void* __restrict__ decays,
                             const void* __restrict__ gate_w, const int* __restrict__ bfp,
                             int l, float* __restrict__ scores) {
    __shared__ float mu_s[D], rstd_s[D], absnb_s[D];
    int t = threadIdx.x, w = t >> 6, ln = t & 63;
    int bf = *bfp;
    {   // finalize stats for feature t; same b-ascending sum as the proven version
        float s = 0.f, q = 0.f;
        #pragma unroll 8
        for (int b = 0; b < NCH; b++) { s += psum[b * D + t]; q += psq[b * D + t]; }
        float m = s / (float)S;
        float var = (q - (float)S * m * m) / (float)(S - 1);   // ddof=1
        float dec = loadf(decays, l, bf);
        float nb = dec * loadf(buffers, l * D + t, bf) + (1.f - dec) * m;
        mu_s[t] = m;
        rstd_s[t] = rsqrtf(var + 1e-6f);
        absnb_s[t] = fabsf(nb);
    }
    __syncthreads();
    int s = blockIdx.x * 4 + w;
    float part = 0.f;
    #pragma unroll
    for (int j = 0; j < 4; j++) {
        int f = ln + j * 64;
        float m = mu_s[f];
        float v = x[(size_t)s * D + f];
        float xv = (fabsf(v - m) > absnb_s[f]) ? m : v;
        xv *= rstd_s[f];
        x[(size_t)s * D + f] = xv;
        part += xv * loadf(gate_w, l * D + f, bf);
    }
    #pragma unroll
    for (int m2 = 1; m2 < 64; m2 <<= 1) part += __shfl_xor(part, m2, 64);
    if (ln == 0) scores[s] = part;
}

// ------- k-th largest via exact MSB radix select (1024 thr, wave-0 scan) ---------
__global__ void k_thr(const float* __restrict__ scores, float* __restrict__ thr) {
    __shared__ unsigned keys[S];
    __shared__ unsigned hist[256];
    __shared__ unsigned sh_pref, sh_rank, sh_bucket;
    int t = threadIdx.x;                     // 1024 threads
    #pragma unroll
    for (int i = 0; i < 4; i++) {
        int idx = i * 1024 + t;
        unsigned u = __float_as_uint(scores[idx]);
        keys[idx] = (u & 0x80000000u) ? ~u : (u | 0x80000000u);   // ascending-monotone
    }
    if (t == 0) { sh_pref = 0u; sh_rank = S - K_GATE; }            // 0-based ascending rank
    __syncthreads();
    for (int shift = 24; shift >= 0; shift -= 8) {
        if (t < 256) hist[t] = 0u;
        __syncthreads();
        unsigned pref = sh_pref, r = sh_rank;
        unsigned pmask = (shift == 24) ? 0u : (0xFFFFFFFFu << (shift + 8));
        #pragma unroll
        for (int i = 0; i < 4; i++) {
            unsigned k = keys[i * 1024 + t];
            if ((k & pmask) == pref) atomicAdd(&hist[(k >> shift) & 0xFF], 1u);
        }
        __syncthreads();
        if (t < 64) {   // wave 0: ordered prefix over 256 buckets, 4/lane
            unsigned h[4];
            unsigned loc = 0u;
            #pragma unroll
            for (int j = 0; j < 4; j++) { h[j] = hist[t * 4 + j]; loc += h[j]; }
            unsigned pre = loc;
            #pragma unroll
            for (int off = 1; off < 64; off <<= 1) {
                unsigned u2 = __shfl_up(pre, off, 64);
                if (t >= off) pre += u2;
            }
            unsigned base = pre - loc;          // exclusive prefix of this lane's chunk
            if (r >= base && r < pre) {         // exactly one lane matches
                unsigned rr = r - base;
                int bsel = -1;
                #pragma unroll
                for (int j = 0; j < 4; j++) {
                    if (bsel < 0) {
                        if (rr < h[j]) bsel = j;
                        else rr -= h[j];
                    }
                }
                sh_bucket = (unsigned)(t * 4 + bsel);
                sh_rank = rr;
            }
        }
        __syncthreads();
        if (t == 0) sh_pref = pref | (sh_bucket << shift);
        __syncthreads();
    }
    if (t == 0) {
        unsigned k = sh_pref;
        unsigned u = (k & 0x80000000u) ? (k ^ 0x80000000u) : ~k;
        thr[0] = __uint_as_float(u);
    }
}

// -------- router (wave per token): gs -> argmin excluded expert ------------------
__global__ void k_route(const float* __restrict__ x, const float* __restrict__ scores,
                        const float* __restrict__ thr,
                        const void* __restrict__ gating_W, const void* __restrict__ gating_b,
                        const int* __restrict__ bfp, int l, int* __restrict__ excl) {
    int t = threadIdx.x, w = t >> 6, ln = t & 63;
    int s = blockIdx.x * 4 + w;
    int bf = *bfp;
    float keep = (scores[s] > thr[0]) ? 1.f : 0.f;
    float xv[4];
    #pragma unroll
    for (int j = 0; j < 4; j++)
        xv[j] = x[(size_t)s * D + ln + j * 64] * keep;
    float gs[E];
    #pragma unroll
    for (int e = 0; e < E; e++) {
        float p = 0.f;
        #pragma unroll
        for (int j = 0; j < 4; j++)
            p += xv[j] * loadf(gating_W, (size_t)(l * E + e) * D + ln + j * 64, bf);
        #pragma unroll
        for (int m2 = 1; m2 < 64; m2 <<= 1) p += __shfl_xor(p, m2, 64);
        gs[e] = p + loadf(gating_b, l * E + e, bf);
    }
    if (ln == 0) {
        // excluded = argmin; ties -> largest index (top_k keeps lower indices)
        int mi = 0;
        float mv = gs[0];
        #pragma unroll
        for (int e = 1; e < E; e++) if (gs[e] <= mv) { mv = gs[e]; mi = e; }
        excl[s] = mi;
    }
}

// ---- fused all-expert GEMM + combine, fp32 VALU, 32x64 tile, M_t=4 x N_t=2 ------
// T14 pipeline: LOAD_REGS(t+1) -> COMPUTE(t) -> barrier -> WRITE_LDS(t+1) -> barrier.
// bf path: B staged as packed bf16 k-pairs in Bsh[E][64][17], expanded at read.
// Grid (4,128)=512 blocks, 256 thr: 2 blocks/CU, 2 waves/SIMD (occupancy rule).
#define MBM 32
#define MBN 64
#define MBK 32
__global__ __launch_bounds__(256) void k_moe(const float* __restrict__ x,
                                             const float* __restrict__ scores,
                                             const float* __restrict__ thr,
                                             const int* __restrict__ excl,
                                             const void* __restrict__ exp_W,
                                             const void* __restrict__ exp_b,
                                             const int* __restrict__ bfp, int l,
                                             float* __restrict__ xo) {
    __shared__ float As[MBK][MBM + 4];                 // row 36 floats = 144 B
    __shared__ __align__(16) char Bmem[E * MBK * (MBN + 4) * 4];   // 34816 B union
    __shared__ float kp[MBM];
    __shared__ int exs[MBM];
    float (*Bsf)[MBK][MBN + 4] = (float (*)[MBK][MBN + 4])Bmem;    // fp32 path
    unsigned (*Bsh)[MBN][17]   = (unsigned (*)[MBN][17])Bmem;      // bf16-pair path
    int bf = *bfp;
    int bnf = blockIdx.x * MBN;   // feature col within D
    int bm = blockIdx.y * MBM;    // token tile
    int t = threadIdx.x;          // 256
    int tm = (t >> 5) * 4;        // 4 token rows / thread (16B-aligned for b128)
    int tn = (t & 31) * 2;        // 2 feature cols / thread (per expert)
    int am = t >> 3, ac4 = t & 7; // A staging coords
    int bn = t >> 2, bc8 = t & 3; // B staging coords
    if (t < MBM) {
        kp[t] = (scores[bm + t] > thr[0]) ? 1.f : 0.f;
        exs[t] = excl[bm + t];
    }
    __syncthreads();
    const unsigned short* Wb16 = (const unsigned short*)exp_W;
    const float* Wf32 = (const float*)exp_W;
    size_t wbase = (size_t)l * E * D * D;

    // ---- T14 register staging state ----
    float4 aReg;
    ushort4 bReg0[E], bReg1[E];   // bf path
    float4 fReg0[E], fReg1[E];    // fp32 fallback path

    // prologue: load tile k0=0 into regs
    aReg = *(const float4*)&x[(size_t)(bm + am) * D + ac4 * 4];
    if (bf) {
        #pragma unroll
        for (int e = 0; e < E; e++) {
            size_t roff = wbase + ((size_t)e * D + bnf + bn) * D + bc8 * 8;
            bReg0[e] = *(const ushort4*)(Wb16 + roff);
            bReg1[e] = *(const ushort4*)(Wb16 + roff + 4);
        }
    } else {
        #pragma unroll
        for (int e = 0; e < E; e++) {
            size_t roff = wbase + ((size_t)e * D + bnf + bn) * D + bc8 * 8;
            fReg0[e] = *(const float4*)(Wf32 + roff);
            fReg1[e] = *(const float4*)(Wf32 + roff + 4);
        }
    }
    // write tile 0 to LDS (gate A during write; pack B pairs)
    {
        float kk = kp[am];
        As[ac4 * 4 + 0][am] = aReg.x * kk;
        As[ac4 * 4 + 1][am] = aReg.y * kk;
        As[ac4 * 4 + 2][am] = aReg.z * kk;
        As[ac4 * 4 + 3][am] = aReg.w * kk;
        if (bf) {
            #pragma unroll
            for (int e = 0; e < E; e++) {
                unsigned* dst = &Bsh[e][bn][bc8 * 4];
                dst[0] = (unsigned)bReg0[e].x | ((unsigned)bReg0[e].y << 16);
                dst[1] = (unsigned)bReg0[e].z | ((unsigned)bReg0[e].w << 16);
                dst[2] = (unsigned)bReg1[e].x | ((unsigned)bReg1[e].y << 16);
                dst[3] = (unsigned)bReg1[e].z | ((unsigned)bReg1[e].w << 16);
            }
        } else {
            #pragma unroll
            for (int e = 0; e < E; e++) {
                Bsf[e][bc8 * 8 + 0][bn] = fReg0[e].x;
                Bsf[e][bc8 * 8 + 1][bn] = fReg0[e].y;
                Bsf[e][bc8 * 8 + 2][bn] = fReg0[e].z;
                Bsf[e][bc8 * 8 + 3][bn] = fReg0[e].w;
                Bsf[e][bc8 * 8 + 4][bn] = fReg1[e].x;
                Bsf[e][bc8 * 8 + 5][bn] = fReg1[e].y;
                Bsf[e][bc8 * 8 + 6][bn] = fReg1[e].z;
                Bsf[e][bc8 * 8 + 7][bn] = fReg1[e].w;
            }
        }
    }
    __syncthreads();

    float acc[E][4][2] = {};
    for (int k0 = 0; k0 < D; k0 += MBK) {
        int kn = k0 + MBK;
        if (kn < D) {   // issue next-tile global loads early (hide under FMA loop)
            aReg = *(const float4*)&x[(size_t)(bm + am) * D + kn + ac4 * 4];
            if (bf) {
                #pragma unroll
                for (int e = 0; e < E; e++) {
                    size_t roff = wbase + ((size_t)e * D + bnf + bn) * D + kn + bc8 * 8;
                    bReg0[e] = *(const ushort4*)(Wb16 + roff);
                    bReg1[e] = *(const ushort4*)(Wb16 + roff + 4);
                }
            } else {
                #pragma unroll
                for (int e = 0; e < E; e++) {
                    size_t roff = wbase + ((size_t)e * D + bnf + bn) * D + kn + bc8 * 8;
                    fReg0[e] = *(const float4*)(Wf32 + roff);
                    fReg1[e] = *(const float4*)(Wf32 + roff + 4);
                }
            }
        }
        // ---- compute tile k0 from LDS (unchanged from R10 -> bit-identical) ----
        if (bf) {
            #pragma unroll 4
            for (int k = 0; k < MBK; k += 2) {
                float4 a0 = *(const float4*)&As[k][tm];       // 4 rows, k
                float4 a1 = *(const float4*)&As[k + 1][tm];   // 4 rows, k+1
                #pragma unroll
                for (int e = 0; e < E; e++) {
                    unsigned w0 = Bsh[e][tn][k >> 1];         // col tn:  (k, k+1)
                    unsigned w1 = Bsh[e][tn + 1][k >> 1];     // col tn+1:(k, k+1)
                    float b00 = __uint_as_float(w0 << 16);          // exact bf16->f32
                    float b01 = __uint_as_float(w0 & 0xFFFF0000u);
                    float b10 = __uint_as_float(w1 << 16);
                    float b11 = __uint_as_float(w1 & 0xFFFF0000u);
                    // k first, then k+1: preserves ascending-k chain per accumulator
                    acc[e][0][0] += a0.x * b00; acc[e][0][1] += a0.x * b10;
                    acc[e][1][0] += a0.y * b00; acc[e][1][1] += a0.y * b10;
                    acc[e][2][0] += a0.z * b00; acc[e][2][1] += a0.z * b10;
                    acc[e][3][0] += a0.w * b00; acc[e][3][1] += a0.w * b10;
                    acc[e][0][0] += a1.x * b01; acc[e][0][1] += a1.x * b11;
                    acc[e][1][0] += a1.y * b01; acc[e][1][1] += a1.y * b11;
                    acc[e][2][0] += a1.z * b01; acc[e][2][1] += a1.z * b11;
                    acc[e][3][0] += a1.w * b01; acc[e][3][1] += a1.w * b11;
                }
            }
        } else {
            #pragma unroll 4
            for (int k = 0; k < MBK; k++) {
                float4 a = *(const float4*)&As[k][tm];
                #pragma unroll
                for (int e = 0; e < E; e++) {
                    float2 b = *(const float2*)&Bsf[e][k][tn];
                    acc[e][0][0] += a.x * b.x;
                    acc[e][0][1] += a.x * b.y;
                    acc[e][1][0] += a.y * b.x;
                    acc[e][1][1] += a.y * b.y;
                    acc[e][2][0] += a.z * b.x;
                    acc[e][2][1] += a.z * b.y;
                    acc[e][3][0] += a.w * b.x;
                    acc[e][3][1] += a.w * b.y;
                }
            }
        }
        __syncthreads();                 // all reads of tile k0 done
        if (kn < D) {                    // write tile kn (implicit vmcnt wait here)
            float kk = kp[am];
            As[ac4 * 4 + 0][am] = aReg.x * kk;
            As[ac4 * 4 + 1][am] = aReg.y * kk;
            As[ac4 * 4 + 2][am] = aReg.z * kk;
            As[ac4 * 4 + 3][am] = aReg.w * kk;
            if (bf) {
                #pragma unroll
                for (int e = 0; e < E; e++) {
                    unsigned* dst = &Bsh[e][bn][bc8 * 4];
                    dst[0] = (unsigned)bReg0[e].x | ((unsigned)bReg0[e].y << 16);
                    dst[1] = (unsigned)bReg0[e].z | ((unsigned)bReg0[e].w << 16);
                    dst[2] = (unsigned)bReg1[e].x | ((unsigned)bReg1[e].y << 16);
                    dst[3] = (unsigned)bReg1[e].z | ((unsigned)bReg1[e].w << 16);
                }
            } else {
                #pragma unroll
                for (int e = 0; e < E; e++) {
                    Bsf[e][bc8 * 8 + 0][bn] = fReg0[e].x;
                    Bsf[e][bc8 * 8 + 1][bn] = fReg0[e].y;
                    Bsf[e][bc8 * 8 + 2][bn] = fReg0[e].z;
                    Bsf[e][bc8 * 8 + 3][bn] = fReg0[e].w;
                    Bsf[e][bc8 * 8 + 4][bn] = fReg1[e].x;
                    Bsf[e][bc8 * 8 + 5][bn] = fReg1[e].y;
                    Bsf[e][bc8 * 8 + 6][bn] = fReg1[e].z;
                    Bsf[e][bc8 * 8 + 7][bn] = fReg1[e].w;
                }
            }
            __syncthreads();             // tile kn visible for next iteration
        }
    }
    // combine: e-ascending, skip excluded, fin += (acc + bias) — proven order
    float fin[4][2] = {};
    #pragma unroll
    for (int e = 0; e < E; e++) {
        float be[2];
        #pragma unroll
        for (int j = 0; j < 2; j++)
            be[j] = loadf(exp_b, (size_t)(l * E + e) * D + bnf + tn + j, bf);
        #pragma unroll
        for (int i = 0; i < 4; i++) {
            if (exs[tm + i] != e) {
                #pragma unroll
                for (int j = 0; j < 2; j++)
                    fin[i][j] += acc[e][i][j] + be[j];
            }
        }
    }
    #pragma unroll
    for (int i = 0; i < 4; i++) {
        float2 o = { fin[i][0], fin[i][1] };
        *(float2*)&xo[(size_t)(bm + tm + i) * D + bnf + tn] = o;
    }
}

// ---------------- final LayerNorm -> bf16 (wave per token) ----------------
__global__ void k_ln(const float* __restrict__ x, const void* __restrict__ g,
                     const void* __restrict__ b, const int* __restrict__ bfp,
                     bf16* __restrict__ xnb) {
    int t = threadIdx.x, w = t >> 6, ln = t & 63;
    int s = blockIdx.x * 4 + w;
    int bf = *bfp;
    float vv[4];
    float sum = 0.f, sq = 0.f;
    #pragma unroll
    for (int j = 0; j < 4; j++) {
        float v = x[(size_t)s * D + ln + j * 64];
        vv[j] = v; sum += v; sq += v * v;
    }
    #pragma unroll
    for (int m2 = 1; m2 < 64; m2 <<= 1) {
        sum += __shfl_xor(sum, m2, 64);
        sq  += __shfl_xor(sq, m2, 64);
    }
    float m = sum / (float)D;
    float var = sq / (float)D - m * m;   // biased
    float r = rsqrtf(var + 1e-5f);
    #pragma unroll
    for (int j = 0; j < 4; j++) {
        int f = ln + j * 64;
        xnb[(size_t)s * D + f] = __float2bfloat16((vv[j] - m) * r * loadf(g, f, bf)
                                                  + loadf(b, f, bf));
    }
}

// ---------------- vocab head: MFMA bf16, 128x128, GLDS staging + CTS epilogue ----
__global__ __launch_bounds__(256) void k_head_mfma(const bf16* __restrict__ xnb,
                                                   const void* __restrict__ head_W_raw,
                                                   const bf16* __restrict__ Wb,
                                                   const void* __restrict__ bias,
                                                   const int* __restrict__ bfp,
                                                   void* __restrict__ out) {
    // union: staging (16 KB) / C-tile 128*CTS shorts (34.8 KB)
    __shared__ __align__(16) char smem[128 * CTS * 2];
    short* At = (short*)smem;            // [128][32] swizzled
    short* Bt = (short*)(smem + 8192);   // [128][32] swizzled
    short* Ct = (short*)smem;            // [128][CTS] bf16 bits
    int bf = *bfp;
    const bf16* Wsrc = bf ? (const bf16*)head_W_raw : Wb;
    int bs = blockIdx.x * 128;   // token tile (x fastest -> W-tile L2 reuse)
    int bv = blockIdx.y * 128;   // vocab tile
    int t = threadIdx.x;
    int wave = t >> 6, lane = t & 63;
    int wm = (wave >> 1) * 64, wn = (wave & 1) * 64;
    int quad = lane >> 4, l16 = lane & 15;

    f32x4 acc[4][4] = {};
    for (int k0 = 0; k0 < D; k0 += 32) {
        stage_tile(xnb + (size_t)bs * D, D, At, t, k0);
        stage_tile(Wsrc + (size_t)bv * D, D, Bt, t, k0);
        __syncthreads();
        bf16x8 af[4], bfg[4];
        #pragma unroll
        for (int i = 0; i < 4; i++) af[i]  = frag_ld(At, wm + i * 16 + l16, quad);
        #pragma unroll
        for (int j = 0; j < 4; j++) bfg[j] = frag_ld(Bt, wn + j * 16 + l16, quad);
        #pragma unroll
        for (int i = 0; i < 4; i++)
            #pragma unroll
            for (int j = 0; j < 4; j++)
                acc[i][j] = __builtin_amdgcn_mfma_f32_16x16x32_bf16(af[i], bfg[j], acc[i][j], 0, 0, 0);
        __syncthreads();
    }
    if (bf) {
        // bias add + pack into LDS C-tile, then 16B/lane coalesced stores
        #pragma unroll
        for (int j = 0; j < 4; j++) {
            int colL = wn + j * 16 + l16;
            float bb = __bfloat162float(((const bf16*)bias)[bv + colL]);
            #pragma unroll
            for (int i = 0; i < 4; i++) {
                int rowL = wm + i * 16 + quad * 4;
                #pragma unroll
                for (int rg = 0; rg < 4; rg++) {
                    bf16 hv = __float2bfloat16(acc[i][j][rg] + bb);
                    Ct[(rowL + rg) * CTS + colL] = *(short*)&hv;
                }
            }
        }
        __syncthreads();
        bf16* ob = (bf16*)out;
        #pragma unroll
        for (int k = 0; k < 8; k++) {
            int cc = k * 256 + t;
            int row = cc >> 4, c16 = cc & 15;
            bf16x8 v = *(const bf16x8*)&Ct[row * CTS + c16 * 8];
            *(bf16x8*)(ob + (size_t)(bs + row) * V + bv + c16 * 8) = v;
        }
    } else {
        float* of = (float*)out;
        #pragma unroll
        for (int j = 0; j < 4; j++) {
            int col = bv + wn + j * 16 + l16;
            float bb = loadf(bias, col, bf);
            #pragma unroll
            for (int i = 0; i < 4; i++) {
                int row0 = bs + wm + i * 16 + quad * 4;
                #pragma unroll
                for (int rg = 0; rg < 4; rg++)
                    of[(size_t)(row0 + rg) * V + col] = acc[i][j][rg] + bb;
            }
        }
    }
}

extern "C" void kernel_launch(void* const* d_in, const int* in_sizes, int n_in,
                              void* d_out, int out_size, void* d_ws, size_t ws_size,
                              hipStream_t stream) {
    const int*  tokens   = (const int*)d_in[0];
    const void* emb      = d_in[1];
    const void* buffers  = d_in[2];
    const void* decays   = d_in[3];
    const void* gate_w   = d_in[4];
    const void* gating_W = d_in[5];
    const void* gating_b = d_in[6];
    const void* exp_W    = d_in[7];
    const void* exp_b    = d_in[8];
    const void* ln_g     = d_in[9];
    const void* ln_b     = d_in[10];
    const void* head_W   = d_in[11];
    const void* head_b   = d_in[12];

    char* p = (char*)d_ws;
    bf16* Wb    = (bf16*)p;             p += (size_t)V * D * 2;       // fp32 fallback
    bf16* xnb   = (bf16*)p;             p += (size_t)S * D * 2;
    float* xA   = (float*)p;            p += (size_t)S * D * 4;
    float* xB   = (float*)p;            p += (size_t)S * D * 4;
    float* psum = (float*)p;            p += (size_t)NCH * D * 4;
    float* psq  = (float*)p;            p += (size_t)NCH * D * 4;
    float* scores = (float*)p;          p += (size_t)S * 4;
    int* excl   = (int*)p;              p += (size_t)S * 4;
    float* thr  = (float*)p;            p += 16;
    int* flag   = (int*)p;              p += 16;

    k_detect<<<1, 1, 0, stream>>>(emb, flag);
    k_wcast<<<(V * D) / 1024, 256, 0, stream>>>(head_W, flag, Wb);
    k_embed<<<S, D, 0, stream>>>(tokens, emb, flag, xA);

    float* xc = xA;
    float* xo = xB;
    for (int l = 0; l < L; l++) {
        k_stats_part<<<NCH, 256, 0, stream>>>(xc, psum, psq);
        k_norm_score<<<S / 4, 256, 0, stream>>>(xc, psum, psq, buffers, decays,
                                                gate_w, flag, l, scores);
        k_thr<<<1, 1024, 0, stream>>>(scores, thr);
        k_route<<<S / 4, 256, 0, stream>>>(xc, scores, thr, gating_W, gating_b,
                                           flag, l, excl);
        dim3 gm(D / MBN, S / MBM);
        k_moe<<<gm, 256, 0, stream>>>(xc, scores, thr, excl, exp_W, exp_b, flag, l, xo);
        float* tmp = xc; xc = xo; xo = tmp;
    }
    k_ln<<<S / 4, 256, 0, stream>>>(xc, ln_g, ln_b, flag, xnb);
    dim3 gh(S / 128, V / 128);
    k_head_mfma<<<gh, 256, 0, stream>>>(xnb, head_W, Wb, head_b, flag, d_out);
}

// Round 13
// 955.154 us; speedup vs baseline: 1.0128x; 1.0128x over previous
//
#include <hip/hip_runtime.h>
#include <hip/hip_bf16.h>
#include <math.h>

#define V 32000
#define D 256
#define L 4
#define E 4
#define S 4096
#define K_GATE 2201   // int(4096 * sigmoid(0.15)) = int(2201.31)
#define NCH 64        // stats chunks
#define SCHUNK 64     // tokens per stats chunk
#define CTS 136       // head C-tile LDS row stride (shorts); 272B=17*16 -> rows 16B-aligned

// Numerics rule (prior-session bisect): the expert GEMM must stay fp32-exact.
// fp32 VALU with k-ascending FMA chains is the proven-safe class. B stays bf16
// BITS in LDS (packed pairs), expanded to fp32 exactly at read (u<<16) -> every
// FMA sees identical fp32 operands in identical k=0..255 ascending order.
//
// Ledger of measured k_moe levers (this session):
//   R9  (M_t,N_t) 2x4 -> 4x2 (72->48 B/32FMA):      -16 us  [byte lever]
//   R10 B as packed bf16 pairs (48->32 B/32FMA):    -12 us  [byte lever, exhausted]
//   R12 T14 issue-early/write-late:                  +5 us  [REVERTED - latency
//        already hidden by 2-waves/SIMD TLP; k_moe is FMA-issue-bound]
// Occupancy rule (R3): k_moe keeps 256 thr x 512 blocks (2 blocks/CU, 2 w/SIMD).
//
// This round: k_head_mfma BK 32->64 (two 32-k sub-tiles per barrier pair).
// Barriers/block 16->8; MFMA order per accumulator unchanged -> bit-identical.

typedef __hip_bfloat16 bf16;
typedef __attribute__((ext_vector_type(8))) short bf16x8;
typedef __attribute__((ext_vector_type(4))) float f32x4;

__device__ __forceinline__ float loadf(const void* p, size_t i, int bf) {
    if (bf) return __bfloat162float(((const bf16*)p)[i]);
    return ((const float*)p)[i];
}
__device__ __forceinline__ float us2f(unsigned short u) {   // bf16 bits -> fp32 (exact)
    return __uint_as_float((unsigned)u << 16);
}

// async global->LDS, 16B per lane; LDS dest = wave-uniform base + lane*16
#define GLDS16(g, l)                                                            \
    __builtin_amdgcn_global_load_lds(                                           \
        (const __attribute__((address_space(1))) unsigned int*)(g),             \
        (__attribute__((address_space(3))) unsigned int*)(l), 16, 0, 0)

// Stage a 128x32 bf16 tile (8 KB) with XOR chunk swizzle (exonerated: bit-identical
// outputs). frag ds_read_b128 lands ~2-way conflict (free).
__device__ __forceinline__ void stage_tile(const bf16* __restrict__ src, int rowStride,
                                           short* lds, int t, int k0) {
    int w = t >> 6, l = t & 63;
    #pragma unroll
    for (int i = 0; i < 2; i++) {
        int chunk = (w * 2 + i) * 64 + l;
        int row = chunk >> 2;
        int c8 = (chunk & 3) ^ ((row >> 1) & 3);
        const bf16* g = src + (size_t)row * rowStride + k0 + c8 * 8;
        GLDS16(g, (char*)lds + (size_t)(w * 2 + i) * 1024);
    }
}

__device__ __forceinline__ bf16x8 frag_ld(const short* lds, int row, int quad) {
    return *(const bf16x8*)&lds[row * 32 + ((quad ^ ((row >> 1) & 3)) << 3)];
}

// ---------------- runtime dtype detection (bf16 vs fp32 inputs) ----------------
__global__ void k_detect(const void* __restrict__ emb, int* __restrict__ flag) {
    const unsigned short* h = (const unsigned short*)emb;
    int cnt = 0;
    for (int i = 0; i < 128; i += 2) {
        int e = (h[i] >> 7) & 0xFF;
        if (e >= 100 && e <= 130) cnt++;
    }
    *flag = (cnt >= 32) ? 1 : 0;
}

// ---------------- head weight -> bf16 (fp32-input fallback only) ----------------
__global__ void k_wcast(const void* __restrict__ W, const int* __restrict__ bfp,
                        bf16* __restrict__ Wb) {
    if (*bfp) return;   // bf16 inputs: head reads W directly
    size_t idx = ((size_t)blockIdx.x * 256 + threadIdx.x) * 4;
    float4 v = *(const float4*)((const float*)W + idx);
    Wb[idx + 0] = __float2bfloat16(v.x);
    Wb[idx + 1] = __float2bfloat16(v.y);
    Wb[idx + 2] = __float2bfloat16(v.z);
    Wb[idx + 3] = __float2bfloat16(v.w);
}

// ---------------- embedding gather ----------------
__global__ void k_embed(const int* __restrict__ tok, const void* __restrict__ emb,
                        const int* __restrict__ bfp, float* __restrict__ x) {
    int s = blockIdx.x, d = threadIdx.x;
    int bf = *bfp;
    int t = tok[s];
    x[s * D + d] = loadf(emb, (size_t)t * D + d, bf);
}

// ---------------- AstroNorm stats, phase 1: coalesced partial sums ----------------
__global__ void k_stats_part(const float* __restrict__ x, float* __restrict__ psum,
                             float* __restrict__ psq) {
    int b = blockIdx.x;        // NCH blocks
    int t = threadIdx.x;       // 256 = one feature per thread
    float s = 0.f, q = 0.f;
    int s0 = b * SCHUNK;
    #pragma unroll 4
    for (int i = 0; i < SCHUNK; i++) {
        float v = x[(size_t)(s0 + i) * D + t];
        s += v; q += v * v;
    }
    psum[b * D + t] = s;
    psq[b * D + t] = q;
}

// ------- AstroNorm finalize (per-block, redundant; bit-identical serial order) ---
// ------- + apply + context-gate score (wave per token) ---------------------------
__global__ void k_norm_score(float* __restrict__ x, const float* __restrict__ psum,
                             const float* __restrict__ psq,
                             const void* __restrict__ buffers, const void* __restrict__ decays,
                             const void* __restrict__ gate_w, const int* __restrict__ bfp,
                             int l, float* __restrict__ scores) {
    __shared__ float mu_s[D], rstd_s[D], absnb_s[D];
    int t = threadIdx.x, w = t >> 6, ln = t & 63;
    int bf = *bfp;
    {   // finalize stats for feature t; same b-ascending sum as the proven version
        float s = 0.f, q = 0.f;
        #pragma unroll 8
        for (int b = 0; b < NCH; b++) { s += psum[b * D + t]; q += psq[b * D + t]; }
        float m = s / (float)S;
        float var = (q - (float)S * m * m) / (float)(S - 1);   // ddof=1
        float dec = loadf(decays, l, bf);
        float nb = dec * loadf(buffers, l * D + t, bf) + (1.f - dec) * m;
        mu_s[t] = m;
        rstd_s[t] = rsqrtf(var + 1e-6f);
        absnb_s[t] = fabsf(nb);
    }
    __syncthreads();
    int s = blockIdx.x * 4 + w;
    float part = 0.f;
    #pragma unroll
    for (int j = 0; j < 4; j++) {
        int f = ln + j * 64;
        float m = mu_s[f];
        float v = x[(size_t)s * D + f];
        float xv = (fabsf(v - m) > absnb_s[f]) ? m : v;
        xv *= rstd_s[f];
        x[(size_t)s * D + f] = xv;
        part += xv * loadf(gate_w, l * D + f, bf);
    }
    #pragma unroll
    for (int m2 = 1; m2 < 64; m2 <<= 1) part += __shfl_xor(part, m2, 64);
    if (ln == 0) scores[s] = part;
}

// ------- k-th largest via exact MSB radix select (1024 thr, wave-0 scan) ---------
__global__ void k_thr(const float* __restrict__ scores, float* __restrict__ thr) {
    __shared__ unsigned keys[S];
    __shared__ unsigned hist[256];
    __shared__ unsigned sh_pref, sh_rank, sh_bucket;
    int t = threadIdx.x;                     // 1024 threads
    #pragma unroll
    for (int i = 0; i < 4; i++) {
        int idx = i * 1024 + t;
        unsigned u = __float_as_uint(scores[idx]);
        keys[idx] = (u & 0x80000000u) ? ~u : (u | 0x80000000u);   // ascending-monotone
    }
    if (t == 0) { sh_pref = 0u; sh_rank = S - K_GATE; }            // 0-based ascending rank
    __syncthreads();
    for (int shift = 24; shift >= 0; shift -= 8) {
        if (t < 256) hist[t] = 0u;
        __syncthreads();
        unsigned pref = sh_pref, r = sh_rank;
        unsigned pmask = (shift == 24) ? 0u : (0xFFFFFFFFu << (shift + 8));
        #pragma unroll
        for (int i = 0; i < 4; i++) {
            unsigned k = keys[i * 1024 + t];
            if ((k & pmask) == pref) atomicAdd(&hist[(k >> shift) & 0xFF], 1u);
        }
        __syncthreads();
        if (t < 64) {   // wave 0: ordered prefix over 256 buckets, 4/lane
            unsigned h[4];
            unsigned loc = 0u;
            #pragma unroll
            for (int j = 0; j < 4; j++) { h[j] = hist[t * 4 + j]; loc += h[j]; }
            unsigned pre = loc;
            #pragma unroll
            for (int off = 1; off < 64; off <<= 1) {
                unsigned u2 = __shfl_up(pre, off, 64);
                if (t >= off) pre += u2;
            }
            unsigned base = pre - loc;          // exclusive prefix of this lane's chunk
            if (r >= base && r < pre) {         // exactly one lane matches
                unsigned rr = r - base;
                int bsel = -1;
                #pragma unroll
                for (int j = 0; j < 4; j++) {
                    if (bsel < 0) {
                        if (rr < h[j]) bsel = j;
                        else rr -= h[j];
                    }
                }
                sh_bucket = (unsigned)(t * 4 + bsel);
                sh_rank = rr;
            }
        }
        __syncthreads();
        if (t == 0) sh_pref = pref | (sh_bucket << shift);
        __syncthreads();
    }
    if (t == 0) {
        unsigned k = sh_pref;
        unsigned u = (k & 0x80000000u) ? (k ^ 0x80000000u) : ~k;
        thr[0] = __uint_as_float(u);
    }
}

// -------- router (wave per token): gs -> argmin excluded expert ------------------
__global__ void k_route(const float* __restrict__ x, const float* __restrict__ scores,
                        const float* __restrict__ thr,
                        const void* __restrict__ gating_W, const void* __restrict__ gating_b,
                        const int* __restrict__ bfp, int l, int* __restrict__ excl) {
    int t = threadIdx.x, w = t >> 6, ln = t & 63;
    int s = blockIdx.x * 4 + w;
    int bf = *bfp;
    float keep = (scores[s] > thr[0]) ? 1.f : 0.f;
    float xv[4];
    #pragma unroll
    for (int j = 0; j < 4; j++)
        xv[j] = x[(size_t)s * D + ln + j * 64] * keep;
    float gs[E];
    #pragma unroll
    for (int e = 0; e < E; e++) {
        float p = 0.f;
        #pragma unroll
        for (int j = 0; j < 4; j++)
            p += xv[j] * loadf(gating_W, (size_t)(l * E + e) * D + ln + j * 64, bf);
        #pragma unroll
        for (int m2 = 1; m2 < 64; m2 <<= 1) p += __shfl_xor(p, m2, 64);
        gs[e] = p + loadf(gating_b, l * E + e, bf);
    }
    if (ln == 0) {
        // excluded = argmin; ties -> largest index (top_k keeps lower indices)
        int mi = 0;
        float mv = gs[0];
        #pragma unroll
        for (int e = 1; e < E; e++) if (gs[e] <= mv) { mv = gs[e]; mi = e; }
        excl[s] = mi;
    }
}

// ---- fused all-expert GEMM + combine, fp32 VALU, 32x64 tile, M_t=4 x N_t=2 ------
// R10-exact (T14 reverted). bf path: B staged as packed bf16 k-pairs in
// Bsh[E][64][17], expanded at read. Grid (4,128)=512 blocks, 256 thr.
#define MBM 32
#define MBN 64
#define MBK 32
__global__ __launch_bounds__(256) void k_moe(const float* __restrict__ x,
                                             const float* __restrict__ scores,
                                             const float* __restrict__ thr,
                                             const int* __restrict__ excl,
                                             const void* __restrict__ exp_W,
                                             const void* __restrict__ exp_b,
                                             const int* __restrict__ bfp, int l,
                                             float* __restrict__ xo) {
    __shared__ float As[MBK][MBM + 4];                 // row 36 floats = 144 B
    __shared__ __align__(16) char Bmem[E * MBK * (MBN + 4) * 4];   // 34816 B union
    __shared__ float kp[MBM];
    __shared__ int exs[MBM];
    float (*Bsf)[MBK][MBN + 4] = (float (*)[MBK][MBN + 4])Bmem;    // fp32 path
    unsigned (*Bsh)[MBN][17]   = (unsigned (*)[MBN][17])Bmem;      // bf16-pair path
    int bf = *bfp;
    int bnf = blockIdx.x * MBN;   // feature col within D
    int bm = blockIdx.y * MBM;    // token tile
    int t = threadIdx.x;          // 256
    int tm = (t >> 5) * 4;        // 4 token rows / thread (16B-aligned for b128)
    int tn = (t & 31) * 2;        // 2 feature cols / thread (per expert)
    if (t < MBM) {
        kp[t] = (scores[bm + t] > thr[0]) ? 1.f : 0.f;
        exs[t] = excl[bm + t];
    }
    __syncthreads();
    const unsigned short* Wb16 = (const unsigned short*)exp_W;
    const float* Wf32 = (const float*)exp_W;
    size_t wbase = (size_t)l * E * D * D;
    float acc[E][4][2] = {};
    for (int k0 = 0; k0 < D; k0 += MBK) {
        {   // A: 32 tokens x 32 k floats, gated during staging (proven pattern)
            int m = t >> 3, c4 = t & 7;
            float4 v = *(const float4*)&x[(size_t)(bm + m) * D + k0 + c4 * 4];
            float kk = kp[m];
            As[c4 * 4 + 0][m] = v.x * kk;
            As[c4 * 4 + 1][m] = v.y * kk;
            As[c4 * 4 + 2][m] = v.z * kk;
            As[c4 * 4 + 3][m] = v.w * kk;
        }
        int n = t >> 2, c8 = t & 3;
        if (bf) {
            #pragma unroll
            for (int e = 0; e < E; e++) {   // B: pack bf16 k-pairs, no conversion
                size_t roff = wbase + ((size_t)e * D + bnf + n) * D + k0 + c8 * 8;
                ushort4 v0 = *(const ushort4*)(Wb16 + roff);
                ushort4 v1 = *(const ushort4*)(Wb16 + roff + 4);
                unsigned* dst = &Bsh[e][n][c8 * 4];
                dst[0] = (unsigned)v0.x | ((unsigned)v0.y << 16);   // k+0,k+1
                dst[1] = (unsigned)v0.z | ((unsigned)v0.w << 16);   // k+2,k+3
                dst[2] = (unsigned)v1.x | ((unsigned)v1.y << 16);   // k+4,k+5
                dst[3] = (unsigned)v1.z | ((unsigned)v1.w << 16);   // k+6,k+7
            }
        } else {
            #pragma unroll
            for (int e = 0; e < E; e++) {   // fp32 fallback: proven layout
                size_t roff = wbase + ((size_t)e * D + bnf + n) * D + k0 + c8 * 8;
                float4 v0 = *(const float4*)(Wf32 + roff);
                float4 v1 = *(const float4*)(Wf32 + roff + 4);
                Bsf[e][c8 * 8 + 0][n] = v0.x;
                Bsf[e][c8 * 8 + 1][n] = v0.y;
                Bsf[e][c8 * 8 + 2][n] = v0.z;
                Bsf[e][c8 * 8 + 3][n] = v0.w;
                Bsf[e][c8 * 8 + 4][n] = v1.x;
                Bsf[e][c8 * 8 + 5][n] = v1.y;
                Bsf[e][c8 * 8 + 6][n] = v1.z;
                Bsf[e][c8 * 8 + 7][n] = v1.w;
            }
        }
        __syncthreads();
        if (bf) {
            #pragma unroll 4
            for (int k = 0; k < MBK; k += 2) {
                float4 a0 = *(const float4*)&As[k][tm];       // 4 rows, k
                float4 a1 = *(const float4*)&As[k + 1][tm];   // 4 rows, k+1
                #pragma unroll
                for (int e = 0; e < E; e++) {
                    unsigned w0 = Bsh[e][tn][k >> 1];         // col tn:  (k, k+1)
                    unsigned w1 = Bsh[e][tn + 1][k >> 1];     // col tn+1:(k, k+1)
                    float b00 = __uint_as_float(w0 << 16);          // exact bf16->f32
                    float b01 = __uint_as_float(w0 & 0xFFFF0000u);
                    float b10 = __uint_as_float(w1 << 16);
                    float b11 = __uint_as_float(w1 & 0xFFFF0000u);
                    // k first, then k+1: preserves ascending-k chain per accumulator
                    acc[e][0][0] += a0.x * b00; acc[e][0][1] += a0.x * b10;
                    acc[e][1][0] += a0.y * b00; acc[e][1][1] += a0.y * b10;
                    acc[e][2][0] += a0.z * b00; acc[e][2][1] += a0.z * b10;
                    acc[e][3][0] += a0.w * b00; acc[e][3][1] += a0.w * b10;
                    acc[e][0][0] += a1.x * b01; acc[e][0][1] += a1.x * b11;
                    acc[e][1][0] += a1.y * b01; acc[e][1][1] += a1.y * b11;
                    acc[e][2][0] += a1.z * b01; acc[e][2][1] += a1.z * b11;
                    acc[e][3][0] += a1.w * b01; acc[e][3][1] += a1.w * b11;
                }
            }
        } else {
            #pragma unroll 4
            for (int k = 0; k < MBK; k++) {
                float4 a = *(const float4*)&As[k][tm];
                #pragma unroll
                for (int e = 0; e < E; e++) {
                    float2 b = *(const float2*)&Bsf[e][k][tn];
                    acc[e][0][0] += a.x * b.x;
                    acc[e][0][1] += a.x * b.y;
                    acc[e][1][0] += a.y * b.x;
                    acc[e][1][1] += a.y * b.y;
                    acc[e][2][0] += a.z * b.x;
                    acc[e][2][1] += a.z * b.y;
                    acc[e][3][0] += a.w * b.x;
                    acc[e][3][1] += a.w * b.y;
                }
            }
        }
        __syncthreads();
    }
    // combine: e-ascending, skip excluded, fin += (acc + bias) — proven order
    float fin[4][2] = {};
    #pragma unroll
    for (int e = 0; e < E; e++) {
        float be[2];
        #pragma unroll
        for (int j = 0; j < 2; j++)
            be[j] = loadf(exp_b, (size_t)(l * E + e) * D + bnf + tn + j, bf);
        #pragma unroll
        for (int i = 0; i < 4; i++) {
            if (exs[tm + i] != e) {
                #pragma unroll
                for (int j = 0; j < 2; j++)
                    fin[i][j] += acc[e][i][j] + be[j];
            }
        }
    }
    #pragma unroll
    for (int i = 0; i < 4; i++) {
        float2 o = { fin[i][0], fin[i][1] };
        *(float2*)&xo[(size_t)(bm + tm + i) * D + bnf + tn] = o;
    }
}

// ---------------- final LayerNorm -> bf16 (wave per token) ----------------
__global__ void k_ln(const float* __restrict__ x, const void* __restrict__ g,
                     const void* __restrict__ b, const int* __restrict__ bfp,
                     bf16* __restrict__ xnb) {
    int t = threadIdx.x, w = t >> 6, ln = t & 63;
    int s = blockIdx.x * 4 + w;
    int bf = *bfp;
    float vv[4];
    float sum = 0.f, sq = 0.f;
    #pragma unroll
    for (int j = 0; j < 4; j++) {
        float v = x[(size_t)s * D + ln + j * 64];
        vv[j] = v; sum += v; sq += v * v;
    }
    #pragma unroll
    for (int m2 = 1; m2 < 64; m2 <<= 1) {
        sum += __shfl_xor(sum, m2, 64);
        sq  += __shfl_xor(sq, m2, 64);
    }
    float m = sum / (float)D;
    float var = sq / (float)D - m * m;   // biased
    float r = rsqrtf(var + 1e-5f);
    #pragma unroll
    for (int j = 0; j < 4; j++) {
        int f = ln + j * 64;
        xnb[(size_t)s * D + f] = __float2bfloat16((vv[j] - m) * r * loadf(g, f, bf)
                                                  + loadf(b, f, bf));
    }
}

// ---------------- vocab head: MFMA bf16, 128x128, BK=64 (2 sub-tiles/phase) ------
// Two 32-k sub-tiles staged per barrier pair into 4 x 8 KB LDS regions (32 KB,
// fits under the 34.8 KB Ct union -> occupancy unchanged). Barriers/block 16->8.
// MFMA sequence per accumulator is the same 8 ascending-k steps -> bit-identical.
__global__ __launch_bounds__(256) void k_head_mfma(const bf16* __restrict__ xnb,
                                                   const void* __restrict__ head_W_raw,
                                                   const bf16* __restrict__ Wb,
                                                   const void* __restrict__ bias,
                                                   const int* __restrict__ bfp,
                                                   void* __restrict__ out) {
    // union: staging (4 x 8 KB = 32 KB) / C-tile 128*CTS shorts (34.8 KB)
    __shared__ __align__(16) char smem[128 * CTS * 2];
    short* At0 = (short*)smem;             // [128][32] swizzled, k half 0
    short* At1 = (short*)(smem + 8192);    // k half 1
    short* Bt0 = (short*)(smem + 16384);
    short* Bt1 = (short*)(smem + 24576);
    short* Ct  = (short*)smem;             // [128][CTS] bf16 bits (epilogue)
    int bf = *bfp;
    const bf16* Wsrc = bf ? (const bf16*)head_W_raw : Wb;
    int bs = blockIdx.x * 128;   // token tile (x fastest -> W-tile L2 reuse)
    int bv = blockIdx.y * 128;   // vocab tile
    int t = threadIdx.x;
    int wave = t >> 6, lane = t & 63;
    int wm = (wave >> 1) * 64, wn = (wave & 1) * 64;
    int quad = lane >> 4, l16 = lane & 15;

    f32x4 acc[4][4] = {};
    for (int k0 = 0; k0 < D; k0 += 64) {
        stage_tile(xnb + (size_t)bs * D, D, At0, t, k0);
        stage_tile(xnb + (size_t)bs * D, D, At1, t, k0 + 32);
        stage_tile(Wsrc + (size_t)bv * D, D, Bt0, t, k0);
        stage_tile(Wsrc + (size_t)bv * D, D, Bt1, t, k0 + 32);
        __syncthreads();
        {   // k half 0 (ascending k preserved)
            bf16x8 af[4], bfg[4];
            #pragma unroll
            for (int i = 0; i < 4; i++) af[i]  = frag_ld(At0, wm + i * 16 + l16, quad);
            #pragma unroll
            for (int j = 0; j < 4; j++) bfg[j] = frag_ld(Bt0, wn + j * 16 + l16, quad);
            #pragma unroll
            for (int i = 0; i < 4; i++)
                #pragma unroll
                for (int j = 0; j < 4; j++)
                    acc[i][j] = __builtin_amdgcn_mfma_f32_16x16x32_bf16(af[i], bfg[j], acc[i][j], 0, 0, 0);
        }
        {   // k half 1
            bf16x8 af[4], bfg[4];
            #pragma unroll
            for (int i = 0; i < 4; i++) af[i]  = frag_ld(At1, wm + i * 16 + l16, quad);
            #pragma unroll
            for (int j = 0; j < 4; j++) bfg[j] = frag_ld(Bt1, wn + j * 16 + l16, quad);
            #pragma unroll
            for (int i = 0; i < 4; i++)
                #pragma unroll
                for (int j = 0; j < 4; j++)
                    acc[i][j] = __builtin_amdgcn_mfma_f32_16x16x32_bf16(af[i], bfg[j], acc[i][j], 0, 0, 0);
        }
        __syncthreads();
    }
    if (bf) {
        // bias add + pack into LDS C-tile, then 16B/lane coalesced stores
        #pragma unroll
        for (int j = 0; j < 4; j++) {
            int colL = wn + j * 16 + l16;
            float bb = __bfloat162float(((const bf16*)bias)[bv + colL]);
            #pragma unroll
            for (int i = 0; i < 4; i++) {
                int rowL = wm + i * 16 + quad * 4;
                #pragma unroll
                for (int rg = 0; rg < 4; rg++) {
                    bf16 hv = __float2bfloat16(acc[i][j][rg] + bb);
                    Ct[(rowL + rg) * CTS + colL] = *(short*)&hv;
                }
            }
        }
        __syncthreads();
        bf16* ob = (bf16*)out;
        #pragma unroll
        for (int k = 0; k < 8; k++) {
            int cc = k * 256 + t;
            int row = cc >> 4, c16 = cc & 15;
            bf16x8 v = *(const bf16x8*)&Ct[row * CTS + c16 * 8];
            *(bf16x8*)(ob + (size_t)(bs + row) * V + bv + c16 * 8) = v;
        }
    } else {
        float* of = (float*)out;
        #pragma unroll
        for (int j = 0; j < 4; j++) {
            int col = bv + wn + j * 16 + l16;
            float bb = loadf(bias, col, bf);
            #pragma unroll
            for (int i = 0; i < 4; i++) {
                int row0 = bs + wm + i * 16 + quad * 4;
                #pragma unroll
                for (int rg = 0; rg < 4; rg++)
                    of[(size_t)(row0 + rg) * V + col] = acc[i][j][rg] + bb;
            }
        }
    }
}

extern "C" void kernel_launch(void* const* d_in, const int* in_sizes, int n_in,
                              void* d_out, int out_size, void* d_ws, size_t ws_size,
                              hipStream_t stream) {
    const int*  tokens   = (const int*)d_in[0];
    const void* emb      = d_in[1];
    const void* buffers  = d_in[2];
    const void* decays   = d_in[3];
    const void* gate_w   = d_in[4];
    const void* gating_W = d_in[5];
    const void* gating_b = d_in[6];
    const void* exp_W    = d_in[7];
    const void* exp_b    = d_in[8];
    const void* ln_g     = d_in[9];
    const void* ln_b     = d_in[10];
    const void* head_W   = d_in[11];
    const void* head_b   = d_in[12];

    char* p = (char*)d_ws;
    bf16* Wb    = (bf16*)p;             p += (size_t)V * D * 2;       // fp32 fallback
    bf16* xnb   = (bf16*)p;             p += (size_t)S * D * 2;
    float* xA   = (float*)p;            p += (size_t)S * D * 4;
    float* xB   = (float*)p;            p += (size_t)S * D * 4;
    float* psum = (float*)p;            p += (size_t)NCH * D * 4;
    float* psq  = (float*)p;            p += (size_t)NCH * D * 4;
    float* scores = (float*)p;          p += (size_t)S * 4;
    int* excl   = (int*)p;              p += (size_t)S * 4;
    float* thr  = (float*)p;            p += 16;
    int* flag   = (int*)p;              p += 16;

    k_detect<<<1, 1, 0, stream>>>(emb, flag);
    k_wcast<<<(V * D) / 1024, 256, 0, stream>>>(head_W, flag, Wb);
    k_embed<<<S, D, 0, stream>>>(tokens, emb, flag, xA);

    float* xc = xA;
    float* xo = xB;
    for (int l = 0; l < L; l++) {
        k_stats_part<<<NCH, 256, 0, stream>>>(xc, psum, psq);
        k_norm_score<<<S / 4, 256, 0, stream>>>(xc, psum, psq, buffers, decays,
                                                gate_w, flag, l, scores);
        k_thr<<<1, 1024, 0, stream>>>(scores, thr);
        k_route<<<S / 4, 256, 0, stream>>>(xc, scores, thr, gating_W, gating_b,
                                           flag, l, excl);
        dim3 gm(D / MBN, S / MBM);
        k_moe<<<gm, 256, 0, stream>>>(xc, scores, thr, excl, exp_W, exp_b, flag, l, xo);
        float* tmp = xc; xc = xo; xo = tmp;
    }
    k_ln<<<S / 4, 256, 0, stream>>>(xc, ln_g, ln_b, flag, xnb);
    dim3 gh(S / 128, V / 128);
    k_head_mfma<<<gh, 256, 0, stream>>>(xnb, head_W, Wb, head_b, flag, d_out);
}